// Round 1
// baseline (286.663 us; speedup 1.0000x reference)
//
#include <hip/hip_runtime.h>

// VQ-VAE quantize + EMA update, MI355X.
// R9: (a) dist_kernel staging rewritten as 2-phase double-buffered pipeline:
//     global_load_lds width-16 + raw s_barrier + counted s_waitcnt vmcnt(4)
//     so next-chunk loads stay in flight across barriers (old __syncthreads
//     forced vmcnt(0) drain every chunk = the latency bound behind 18% Mfma /
//     37% VALU / 5.9% HBM). 16 chunks x 16KB, dbuf 32KB -> LDS unchanged
//     (4 blocks/CU). ee hoisted to LDS so no stray vmcnt events in the loop.
//     MFMA math order unchanged (bit-identical dist values).
//     (b) recheck_kernel: 64 barriers/tile -> 5. Per-thread (bd,bi) to LDS,
//     ONE barrier, each wave lex-min-reduces 2 rows by shuffle and applies
//     the out_q/diff fix wave-locally (lex-min is associative => identical
//     results). Grid 256 -> 512.

#define N_ROWS 131072
#define DIM    64
#define NEMB   1024
#define FLAG_CAP 131072
#define TAU 0.02f
#define NRANGE 32

static constexpr float DECAYF = 0.99f;
static constexpr float OMDF   = (float)(1.0 - 0.99);
static constexpr float EPSF   = 1e-5f;
static constexpr float NEPSF  = (float)(1024 * 1e-5);

typedef __attribute__((ext_vector_type(8))) short short8;
typedef __attribute__((ext_vector_type(4))) float f32x4;

static __device__ __forceinline__ unsigned short f2bf(float f) {
    unsigned int u = __builtin_bit_cast(unsigned int, f);
    unsigned int r = (u + 0x7FFFu + ((u >> 16) & 1u)) >> 16;   // RNE
    return (unsigned short)r;
}
static __device__ __forceinline__ float bf2f(unsigned short h) {
    unsigned int u = ((unsigned int)h) << 16;
    return __builtin_bit_cast(float, u);
}

// async global->LDS, 16B per lane; lds base must be wave-uniform.
static __device__ __forceinline__ void glds16(const uint4* g, uint4* l) {
    __builtin_amdgcn_global_load_lds(
        (const __attribute__((address_space(1))) unsigned int*)(g),
        (__attribute__((address_space(3))) unsigned int*)(l), 16, 0, 0);
}

// ws layout (float offsets)
#define WS_ESUM    0         // 65536 (atomic-fallback target)
#define WS_CNTF    65536     // 1024  (atomic-fallback counts)
#define WS_DIFF    66560     // 1
#define WS_FLAGCNT 66561     // 1 (int)
#define WS_N       66562     // 1
#define WS_EE      66564     // 1024
#define WS_EMBEDT  67588     // 65536 (16B aligned)
#define WS_IDX     133124    // 131072 (int)
#define WS_FLAGLST 264196    // 131072 (int)
#define WS_BFRAG   395268    // 65536 floats = 256 KB (16B aligned)
#define WS_CNTPART 460804    // 32768 (NRANGE x 1024)
#define WS_PART    493572    // NRANGE x 65536 = 2097152 floats (16B aligned)
#define WS_NEED_BYTES ((size_t)(WS_PART + NRANGE * 65536) * 4)

// ---------------- prep: embedT, ee, hi/lo fragments of B' = -2*embed
__global__ void prep_kernel(const float* __restrict__ embed,
                            float* __restrict__ embedT,
                            float* __restrict__ ee,
                            uint4* __restrict__ BfragG) {
    int tid = blockIdx.x * 256 + threadIdx.x;      // 0..16383
    for (int i = 0; i < 4; ++i) {
        int id = i * 16384 + tid;
        int d = id >> 10, e = id & 1023;
        embedT[e * 64 + d] = embed[id];
    }
    if (tid < NEMB) {
        float s = 0.f;
        for (int d = 0; d < DIM; ++d) {
            float v = embed[d * 1024 + tid];
            s = fmaf(v, v, s);
        }
        ee[tid] = s;
    }
    int fid  = tid >> 6;            // 0..255
    int lane = tid & 63;
    int hl = fid & 1, kt = (fid >> 1) & 1, ct = fid >> 2;
    int col = ct * 16 + (lane & 15);
    int k0  = kt * 32 + (lane >> 4) * 8;
    unsigned short u[8];
    #pragma unroll
    for (int j = 0; j < 8; ++j) {
        float v = -2.0f * embed[(k0 + j) * 1024 + col];
        unsigned short h = f2bf(v);
        if (hl) h = f2bf(v - bf2f(h));
        u[j] = h;
    }
    uint4 wv;
    wv.x = (unsigned)u[0] | ((unsigned)u[1] << 16);
    wv.y = (unsigned)u[2] | ((unsigned)u[3] << 16);
    wv.z = (unsigned)u[4] | ((unsigned)u[5] << 16);
    wv.w = (unsigned)u[6] | ((unsigned)u[7] << 16);
    BfragG[fid * 64 + lane] = wv;
}

// ---------------- dist: hi/lo MFMA + best2 + quantize + diff
// R9: 16 chunks x 1024 uint4 (16KB), double-buffered, global_load_lds + raw
// barriers + counted vmcnt. Compute math identical to R7/R8.
__global__ __launch_bounds__(256) void dist_kernel(
        const float* __restrict__ x, const uint4* __restrict__ BfragG,
        const float* __restrict__ ee, const float* __restrict__ embedT,
        float* __restrict__ out_q, float* __restrict__ out_ind,
        int* __restrict__ ws_idx, float* __restrict__ ws_diff,
        int* __restrict__ ws_flagcnt, int* __restrict__ ws_flaglist) {
    __shared__ uint4 Bs[2][1024];         // 2 x 16 KB
    __shared__ float sEE[1024];           // 4 KB
    __shared__ int   sIdx[128];
    __shared__ float red[4];

    const int t = threadIdx.x;
    const int w = t >> 6, lane = t & 63;
    const int quad = lane >> 4, wl = lane & 15;
    const int rbase = blockIdx.x * 128;

    short8 a_hi[2][2], a_lo[2][2];
    #pragma unroll
    for (int rt = 0; rt < 2; ++rt) {
        int row = rbase + w * 32 + rt * 16 + wl;
        #pragma unroll
        for (int kt = 0; kt < 2; ++kt) {
            const float* px = x + (size_t)row * 64 + kt * 32 + quad * 8;
            float4 v0 = *(const float4*)px;
            float4 v1 = *(const float4*)(px + 4);
            float vv[8] = {v0.x, v0.y, v0.z, v0.w, v1.x, v1.y, v1.z, v1.w};
            short8 ah, al;
            #pragma unroll
            for (int j = 0; j < 8; ++j) {
                unsigned short h = f2bf(vv[j]);
                ah[j] = (short)h;
                al[j] = (short)f2bf(vv[j] - bf2f(h));
            }
            a_hi[rt][kt] = ah; a_lo[rt][kt] = al;
        }
    }

    // ee -> LDS (keeps the main loop free of extra vmcnt events)
    for (int i = t; i < 1024; i += 256) sEE[i] = ee[i];

    float b1[8], b2[8];
    int   i1[8];
    #pragma unroll
    for (int s = 0; s < 8; ++s) { b1[s] = 3.4e38f; b2[s] = 3.4e38f; i1[s] = 0; }

    const f32x4 zacc = {0.f, 0.f, 0.f, 0.f};

    __syncthreads();                      // sEE visible; clean vm/lgkm slate

#define STAGE(chv, bv)                                                     \
    {                                                                      \
        const uint4* _src = BfragG + (chv) * 1024 + w * 256 + lane;        \
        uint4* _dst = &Bs[bv][w * 256];                                    \
        glds16(_src,       _dst);                                          \
        glds16(_src + 64,  _dst + 64);                                     \
        glds16(_src + 128, _dst + 128);                                    \
        glds16(_src + 192, _dst + 192);                                    \
    }

    int buf = 0;
    STAGE(0, 0);
    for (int ch = 0; ch < 16; ++ch) {
        if (ch < 15) {
            STAGE(ch + 1, buf ^ 1);
            asm volatile("s_waitcnt vmcnt(4)" ::: "memory");  // drain chunk ch only
        } else {
            asm volatile("s_waitcnt vmcnt(0)" ::: "memory");
        }
        __builtin_amdgcn_s_barrier();
        asm volatile("" ::: "memory");    // pin ds_reads below the barrier

        const short8* bp = (const short8*)&Bs[buf][0];
        #pragma unroll
        for (int ctl = 0; ctl < 4; ++ctl) {
            short8 bh0 = bp[(ctl * 4 + 0) * 64 + lane];
            short8 bl0 = bp[(ctl * 4 + 1) * 64 + lane];
            short8 bh1 = bp[(ctl * 4 + 2) * 64 + lane];
            short8 bl1 = bp[(ctl * 4 + 3) * 64 + lane];
            int col = ch * 64 + ctl * 16 + wl;
            float eec = sEE[col];
            #pragma unroll
            for (int rt = 0; rt < 2; ++rt) {
                f32x4 c0 = __builtin_amdgcn_mfma_f32_16x16x32_bf16(a_lo[rt][0], bh0, zacc, 0, 0, 0);
                f32x4 c1 = __builtin_amdgcn_mfma_f32_16x16x32_bf16(a_lo[rt][1], bh1, zacc, 0, 0, 0);
                c0 = __builtin_amdgcn_mfma_f32_16x16x32_bf16(a_hi[rt][0], bl0, c0, 0, 0, 0);
                c1 = __builtin_amdgcn_mfma_f32_16x16x32_bf16(a_hi[rt][1], bl1, c1, 0, 0, 0);
                c0 = __builtin_amdgcn_mfma_f32_16x16x32_bf16(a_hi[rt][0], bh0, c0, 0, 0, 0);
                c1 = __builtin_amdgcn_mfma_f32_16x16x32_bf16(a_hi[rt][1], bh1, c1, 0, 0, 0);
                #pragma unroll
                for (int reg = 0; reg < 4; ++reg) {
                    float s = c0[reg] + c1[reg] + eec;          // v_add3_f32
                    int st = rt * 4 + reg;
                    bool lt = s < b1[st];
                    b2[st] = fminf(fmaxf(s, b1[st]), b2[st]);
                    i1[st] = lt ? col : i1[st];
                    b1[st] = fminf(s, b1[st]);
                }
            }
        }
        asm volatile("s_waitcnt lgkmcnt(0)" ::: "memory");  // ds_reads landed
        __builtin_amdgcn_s_barrier();     // safe to overwrite Bs[buf] next iter
        buf ^= 1;
    }
#undef STAGE

    for (int m = 1; m < 16; m <<= 1) {
        #pragma unroll
        for (int s = 0; s < 8; ++s) {
            float ob1 = __shfl_xor(b1[s], m);
            int   oi1 = __shfl_xor(i1[s], m);
            float ob2 = __shfl_xor(b2[s], m);
            if (ob1 < b1[s] || (ob1 == b1[s] && oi1 < i1[s])) {
                b2[s] = fminf(b1[s], ob2); b1[s] = ob1; i1[s] = oi1;
            } else {
                b2[s] = fminf(b2[s], ob1);
            }
        }
    }
    if (wl == 0) {
        #pragma unroll
        for (int s = 0; s < 8; ++s) {
            int rt = s >> 2, reg = s & 3;
            int rloc = w * 32 + rt * 16 + quad * 4 + reg;
            int row = rbase + rloc;
            sIdx[rloc] = i1[s];
            ws_idx[row] = i1[s];
            out_ind[row] = (float)i1[s];
            if (b2[s] - b1[s] < TAU) {
                int pos = atomicAdd(ws_flagcnt, 1);
                if (pos < FLAG_CAP) ws_flaglist[pos] = row;
            }
        }
    }
    __syncthreads();

    {
        int r = t >> 1, hh = t & 1;
        int e = sIdx[r];
        const float4* et = (const float4*)(embedT + e * 64 + hh * 32);
        const float4* xr = (const float4*)(x + (size_t)(rbase + r) * 64 + hh * 32);
        float4*       qo = (float4*)(out_q + (size_t)(rbase + r) * 64 + hh * 32);
        float dsum = 0.f;
        #pragma unroll
        for (int v = 0; v < 8; ++v) {
            float4 q4 = et[v];
            float4 x4 = xr[v];
            float dx = q4.x - x4.x, dy = q4.y - x4.y, dz = q4.z - x4.z, dw = q4.w - x4.w;
            float4 o;
            o.x = x4.x + dx; o.y = x4.y + dy; o.z = x4.z + dz; o.w = x4.w + dw;
            qo[v] = o;
            dsum += dx * dx + dy * dy + dz * dz + dw * dw;
        }
        for (int o2 = 32; o2 > 0; o2 >>= 1) dsum += __shfl_down(dsum, o2);
        if (lane == 0) red[w] = dsum;
        __syncthreads();
        if (t == 0) atomicAdd(ws_diff, red[0] + red[1] + red[2] + red[3]);
    }
}

// ---------------- recheck: tiled exact fp32 re-argmin
// R9: per-thread (bd,bi) -> LDS, 1 barrier, wave-parallel lex-min reduce
// (associative => identical result), wave-local out_q/diff fix.
__global__ __launch_bounds__(256) void recheck_kernel(
        const float* __restrict__ x, const float* __restrict__ embed,
        const float* __restrict__ embedT, const float* __restrict__ ee,
        const int* __restrict__ flagcnt, const int* __restrict__ flaglist,
        int* __restrict__ ws_idx, float* __restrict__ out_ind,
        float* __restrict__ out_q, float* __restrict__ ws_diff) {
    __shared__ float sx[8][64];
    __shared__ float sff[8];
    __shared__ int   srow[8];
    __shared__ float sbd[8][256];
    __shared__ int   sbi[8][256];
    const int t = threadIdx.x;
    const int w = t >> 6, lane = t & 63;
    int cnt = *flagcnt;
    if (cnt > FLAG_CAP) cnt = FLAG_CAP;
    int ntiles = (cnt + 7) >> 3;
    for (int tile = blockIdx.x; tile < ntiles; tile += gridDim.x) {
        int base = tile * 8;
        int nr = cnt - base; if (nr > 8) nr = 8;
        __syncthreads();                               // LDS reuse guard
        if (t < nr) srow[t] = flaglist[base + t];
        __syncthreads();
        for (int l = t; l < nr * 64; l += 256)
            sx[l >> 6][l & 63] = x[(size_t)srow[l >> 6] * 64 + (l & 63)];
        __syncthreads();
        if (t < nr) {
            float ff = 0.f;
            for (int k = 0; k < 64; ++k) ff = fmaf(sx[t][k], sx[t][k], ff);
            sff[t] = ff;
        }
        float acc[8][4];
        #pragma unroll
        for (int r = 0; r < 8; ++r)
            #pragma unroll
            for (int j = 0; j < 4; ++j) acc[r][j] = 0.f;
        int c0 = t * 4;
        for (int k = 0; k < 64; ++k) {
            float4 e4 = *(const float4*)(embed + k * 1024 + c0);
            #pragma unroll
            for (int r = 0; r < 8; ++r) {
                float xk = sx[r][k];
                acc[r][0] = fmaf(xk, e4.x, acc[r][0]);
                acc[r][1] = fmaf(xk, e4.y, acc[r][1]);
                acc[r][2] = fmaf(xk, e4.z, acc[r][2]);
                acc[r][3] = fmaf(xk, e4.w, acc[r][3]);
            }
        }
        __syncthreads();                               // sff visible
        #pragma unroll
        for (int r = 0; r < 8; ++r) {
            float ff = sff[r];
            float bd = 3.4e38f; int bi = 0;
            #pragma unroll
            for (int j = 0; j < 4; ++j) {
                float d = (ff - 2.f * acc[r][j]) + ee[c0 + j];
                if (d < bd) { bd = d; bi = c0 + j; }
            }
            sbd[r][t] = bd; sbi[r][t] = bi;
        }
        __syncthreads();
        #pragma unroll
        for (int rr = 0; rr < 2; ++rr) {
            int r = w * 2 + rr;
            if (r < nr) {
                float bd = sbd[r][lane]; int bi = sbi[r][lane];
                #pragma unroll
                for (int k2 = 1; k2 < 4; ++k2) {
                    float od = sbd[r][lane + 64 * k2];
                    int   oi = sbi[r][lane + 64 * k2];
                    if (od < bd || (od == bd && oi < bi)) { bd = od; bi = oi; }
                }
                for (int m = 32; m > 0; m >>= 1) {
                    float od = __shfl_xor(bd, m);
                    int   oi = __shfl_xor(bi, m);
                    if (od < bd || (od == bd && oi < bi)) { bd = od; bi = oi; }
                }
                int row = srow[r];
                int oi_old = ws_idx[row];               // broadcast load
                if (bi != oi_old) {
                    float xv = sx[r][lane];
                    float dn   = embedT[bi * 64 + lane] - xv;
                    float dold = embedT[oi_old * 64 + lane] - xv;
                    out_q[(size_t)row * 64 + lane] = xv + dn;
                    float delta = dn * dn - dold * dold;
                    for (int o = 32; o > 0; o >>= 1) delta += __shfl_down(delta, o);
                    if (lane == 0) {
                        ws_idx[row] = bi;
                        out_ind[row] = (float)bi;
                        atomicAdd(ws_diff, delta);
                    }
                }
            }
        }
    }
}

// ---------------- scatter: 32 ranges x 8 dim-octants; LDS hist [8 dims][1024 codes]
__global__ __launch_bounds__(256) void scatter_kernel(
        const int* __restrict__ idx, const float* __restrict__ x,
        float* __restrict__ part_or_esum, float* __restrict__ cntp_or_cntf,
        int use_atomic) {
    __shared__ float shist[8192];         // [8 dims][1024 codes] = 32 KB
    __shared__ float scnt[1024];          // used by oct==0 blocks
    const int t = threadIdx.x;
    const int rb = blockIdx.x >> 3, oct = blockIdx.x & 7;      // 32 ranges x 8
    const int w = t >> 6, lane = t & 63;
    const int g = lane >> 3, d = lane & 7;                     // 8 rows x 8 dims

    for (int i = t; i < 8192; i += 256) shist[i] = 0.f;
    if (oct == 0) for (int i = t; i < 1024; i += 256) scnt[i] = 0.f;
    __syncthreads();

    const int row0 = rb * 4096 + w * 1024;
    int rcur = row0 + g;
    int e_n = idx[rcur];
    float x_n = x[(size_t)rcur * 64 + oct * 8 + d];
    for (int it = 0; it < 128; ++it) {                 // 128 x 8 rows per wave
        int e = e_n; float xv = x_n;
        int rnext = rcur + 8;
        if (it < 127) {                                // prefetch next iteration
            e_n = idx[rnext];
            x_n = x[(size_t)rnext * 64 + oct * 8 + d];
        }
        rcur = rnext;
        atomicAdd(&shist[d * 1024 + e], xv);
        if (oct == 0 && d == 0) atomicAdd(&scnt[e], 1.0f);
    }
    __syncthreads();

    if (!use_atomic) {
        float* dst = part_or_esum + (size_t)blockIdx.x * 8192;
        for (int cell = t; cell < 8192; cell += 256) dst[cell] = shist[cell];
        if (oct == 0) {
            float* cdst = cntp_or_cntf + rb * 1024;
            for (int i = t; i < 1024; i += 256) cdst[i] = scnt[i];
        }
    } else {
        for (int cell = t; cell < 8192; cell += 256) {
            float v = shist[cell];
            if (v != 0.f)
                atomicAdd(&part_or_esum[(oct * 8 + (cell >> 10)) * 1024 + (cell & 1023)], v);
        }
        if (oct == 0) {
            for (int i = t; i < 1024; i += 256) {
                float c = scnt[i];
                if (c != 0.f) atomicAdd(&cntp_or_cntf[i], c);
            }
        }
    }
}

// ---------------- finalize1: counts reduce + new_cluster_size, n, diff
__global__ __launch_bounds__(1024) void finalize1(
        const float* __restrict__ cluster_size, const float* __restrict__ cntp,
        int nrb, const float* __restrict__ ws_diff, float* __restrict__ out_diff,
        float* __restrict__ out_ncs, float* __restrict__ ws_n) {
    int t = threadIdx.x;
    float c = 0.f;
    for (int k = 0; k < nrb; ++k) c += cntp[k * 1024 + t];
    float ncs = DECAYF * cluster_size[t] + OMDF * c;
    out_ncs[t] = ncs;
    __shared__ float sred[16];
    float v = ncs;
    for (int o = 32; o > 0; o >>= 1) v += __shfl_down(v, o);
    if ((t & 63) == 0) sred[t >> 6] = v;
    __syncthreads();
    if (t == 0) {
        float n = 0.f;
        for (int i = 0; i < 16; ++i) n += sred[i];
        ws_n[0] = n;
        out_diff[0] = ws_diff[0] * (1.0f / 8388608.0f);   // /2^23 exact
    }
}

// ---------------- finalize2: partials reduce + new_embed_avg, new_embed
__global__ __launch_bounds__(256) void finalize2(
        const float* __restrict__ embed_avg, const float* __restrict__ part,
        int nrb, const float* __restrict__ out_ncs, const float* __restrict__ ws_n,
        float* __restrict__ out_nea, float* __restrict__ out_ne) {
    int j = blockIdx.x * 256 + threadIdx.x;      // < 65536 = dim*1024 + code
    float es = 0.f;
    for (int k = 0; k < nrb; ++k) es += part[(size_t)k * 65536 + j];
    float n = ws_n[0];
    float nea = DECAYF * embed_avg[j] + OMDF * es;
    out_nea[j] = nea;
    float ncs = out_ncs[j & 1023];
    float cs = (ncs + EPSF) / (n + NEPSF) * n;
    out_ne[j] = nea / cs;
}

extern "C" void kernel_launch(void* const* d_in, const int* in_sizes, int n_in,
                              void* d_out, int out_size, void* d_ws, size_t ws_size,
                              hipStream_t stream) {
    const float* x            = (const float*)d_in[0];
    const float* embed        = (const float*)d_in[1];
    const float* cluster_size = (const float*)d_in[2];
    const float* embed_avg    = (const float*)d_in[3];

    float* out = (float*)d_out;
    float* out_q    = out;                       // 8388608
    float* out_diff = out + 8388608;             // 1
    float* out_ind  = out + 8388609;             // 131072
    float* out_ncs  = out + 8519681;             // 1024
    float* out_nea  = out + 8520705;             // 65536
    float* out_ne   = out + 8586241;             // 65536

    float* ws = (float*)d_ws;
    float* ws_esum     = ws + WS_ESUM;
    float* ws_cntf     = ws + WS_CNTF;
    float* ws_diff     = ws + WS_DIFF;
    int*   ws_flagcnt  = (int*)(ws + WS_FLAGCNT);
    float* ws_n        = ws + WS_N;
    float* ws_ee       = ws + WS_EE;
    float* ws_embedT   = ws + WS_EMBEDT;
    int*   ws_idx      = (int*)(ws + WS_IDX);
    int*   ws_flaglist = (int*)(ws + WS_FLAGLST);
    uint4* ws_Bfrag    = (uint4*)(ws + WS_BFRAG);
    float* ws_cntpart  = ws + WS_CNTPART;
    float* ws_part     = ws + WS_PART;

    const int use_part = (ws_size >= WS_NEED_BYTES) ? 1 : 0;

    if (use_part) {
        hipMemsetAsync(ws + WS_DIFF, 0, 8, stream);          // diff + flagcnt only
    } else {
        hipMemsetAsync(d_ws, 0, (size_t)(WS_FLAGCNT + 1) * 4, stream);
    }

    prep_kernel<<<64, 256, 0, stream>>>(embed, ws_embedT, ws_ee, ws_Bfrag);
    dist_kernel<<<N_ROWS / 128, 256, 0, stream>>>(x, ws_Bfrag, ws_ee, ws_embedT,
                                                  out_q, out_ind, ws_idx, ws_diff,
                                                  ws_flagcnt, ws_flaglist);
    recheck_kernel<<<512, 256, 0, stream>>>(x, embed, ws_embedT, ws_ee,
                                            ws_flagcnt, ws_flaglist,
                                            ws_idx, out_ind, out_q, ws_diff);
    scatter_kernel<<<NRANGE * 8, 256, 0, stream>>>(
        ws_idx, x,
        use_part ? ws_part : ws_esum,
        use_part ? ws_cntpart : ws_cntf,
        use_part ? 0 : 1);
    finalize1<<<1, 1024, 0, stream>>>(cluster_size,
                                      use_part ? ws_cntpart : ws_cntf,
                                      use_part ? NRANGE : 1,
                                      ws_diff, out_diff, out_ncs, ws_n);
    finalize2<<<256, 256, 0, stream>>>(embed_avg,
                                       use_part ? ws_part : ws_esum,
                                       use_part ? NRANGE : 1,
                                       out_ncs, ws_n, out_nea, out_ne);
}

// Round 3
// 269.508 us; speedup vs baseline: 1.0637x; 1.0637x over previous
//
#include <hip/hip_runtime.h>

// VQ-VAE quantize + EMA update, MI355X.
// R11 == R10 resubmit (container infra failure, kernel never measured), with
//     __launch_bounds__(256) instead of (256,4) to avoid any VGPR-cap spill
//     interaction (grid already caps co-residency at 4 blocks/CU).
// R10: (a) dist_kernel: B read DIRECTLY from L2 into registers (rotating
//     1-group prefetch), no LDS staging of B, ZERO barriers in the main loop.
//     R8(sync)==R9(async dbuf)==~120us proved staging micro-structure is not
//     the bottleneck; the barrier-coupled convoy + thin per-wave ILP is.
//     BfragG (256KB) is L2-resident on every XCD, so 4x read amplification
//     costs ~30us of L2 BW, far under the 120us we pay now. MFMA order per
//     (rt, col-group) unchanged => bit-identical results. LDS 37.9KB -> 4.6KB.
//     (b) scatter_kernel: shist layout [d][e] -> [e][d] (kills the 8-way
//     bank conflict: d*1024 = 0 mod 32 put all 8 d-lanes in one bank);
//     512 threads/block (8 waves, 64 iters). Output slab layout unchanged.

#define N_ROWS 131072
#define DIM    64
#define NEMB   1024
#define FLAG_CAP 131072
#define TAU 0.02f
#define NRANGE 32

static constexpr float DECAYF = 0.99f;
static constexpr float OMDF   = (float)(1.0 - 0.99);
static constexpr float EPSF   = 1e-5f;
static constexpr float NEPSF  = (float)(1024 * 1e-5);

typedef __attribute__((ext_vector_type(8))) short short8;
typedef __attribute__((ext_vector_type(4))) float f32x4;

static __device__ __forceinline__ unsigned short f2bf(float f) {
    unsigned int u = __builtin_bit_cast(unsigned int, f);
    unsigned int r = (u + 0x7FFFu + ((u >> 16) & 1u)) >> 16;   // RNE
    return (unsigned short)r;
}
static __device__ __forceinline__ float bf2f(unsigned short h) {
    unsigned int u = ((unsigned int)h) << 16;
    return __builtin_bit_cast(float, u);
}

// ws layout (float offsets)
#define WS_ESUM    0         // 65536 (atomic-fallback target)
#define WS_CNTF    65536     // 1024  (atomic-fallback counts)
#define WS_DIFF    66560     // 1
#define WS_FLAGCNT 66561     // 1 (int)
#define WS_N       66562     // 1
#define WS_EE      66564     // 1024
#define WS_EMBEDT  67588     // 65536 (16B aligned)
#define WS_IDX     133124    // 131072 (int)
#define WS_FLAGLST 264196    // 131072 (int)
#define WS_BFRAG   395268    // 65536 floats = 256 KB (16B aligned)
#define WS_CNTPART 460804    // 32768 (NRANGE x 1024)
#define WS_PART    493572    // NRANGE x 65536 = 2097152 floats (16B aligned)
#define WS_NEED_BYTES ((size_t)(WS_PART + NRANGE * 65536) * 4)

// ---------------- prep: embedT, ee, hi/lo fragments of B' = -2*embed
__global__ void prep_kernel(const float* __restrict__ embed,
                            float* __restrict__ embedT,
                            float* __restrict__ ee,
                            uint4* __restrict__ BfragG) {
    int tid = blockIdx.x * 256 + threadIdx.x;      // 0..16383
    for (int i = 0; i < 4; ++i) {
        int id = i * 16384 + tid;
        int d = id >> 10, e = id & 1023;
        embedT[e * 64 + d] = embed[id];
    }
    if (tid < NEMB) {
        float s = 0.f;
        for (int d = 0; d < DIM; ++d) {
            float v = embed[d * 1024 + tid];
            s = fmaf(v, v, s);
        }
        ee[tid] = s;
    }
    int fid  = tid >> 6;            // 0..255
    int lane = tid & 63;
    int hl = fid & 1, kt = (fid >> 1) & 1, ct = fid >> 2;
    int col = ct * 16 + (lane & 15);
    int k0  = kt * 32 + (lane >> 4) * 8;
    unsigned short u[8];
    #pragma unroll
    for (int j = 0; j < 8; ++j) {
        float v = -2.0f * embed[(k0 + j) * 1024 + col];
        unsigned short h = f2bf(v);
        if (hl) h = f2bf(v - bf2f(h));
        u[j] = h;
    }
    uint4 wv;
    wv.x = (unsigned)u[0] | ((unsigned)u[1] << 16);
    wv.y = (unsigned)u[2] | ((unsigned)u[3] << 16);
    wv.z = (unsigned)u[4] | ((unsigned)u[5] << 16);
    wv.w = (unsigned)u[6] | ((unsigned)u[7] << 16);
    BfragG[fid * 64 + lane] = wv;
}

// ---------------- dist: hi/lo MFMA + best2 + quantize + diff
// R10/R11: B fragments streamed from L2 into registers (1-group rotating
// prefetch). No LDS for B, no main-loop barriers. Math order identical.
__global__ __launch_bounds__(256) void dist_kernel(
        const float* __restrict__ x, const uint4* __restrict__ BfragG,
        const float* __restrict__ ee, const float* __restrict__ embedT,
        float* __restrict__ out_q, float* __restrict__ out_ind,
        int* __restrict__ ws_idx, float* __restrict__ ws_diff,
        int* __restrict__ ws_flagcnt, int* __restrict__ ws_flaglist) {
    __shared__ float sEE[1024];           // 4 KB
    __shared__ int   sIdx[128];
    __shared__ float red[4];

    const int t = threadIdx.x;
    const int w = t >> 6, lane = t & 63;
    const int quad = lane >> 4, wl = lane & 15;
    const int rbase = blockIdx.x * 128;

    short8 a_hi[2][2], a_lo[2][2];
    #pragma unroll
    for (int rt = 0; rt < 2; ++rt) {
        int row = rbase + w * 32 + rt * 16 + wl;
        #pragma unroll
        for (int kt = 0; kt < 2; ++kt) {
            const float* px = x + (size_t)row * 64 + kt * 32 + quad * 8;
            float4 v0 = *(const float4*)px;
            float4 v1 = *(const float4*)(px + 4);
            float vv[8] = {v0.x, v0.y, v0.z, v0.w, v1.x, v1.y, v1.z, v1.w};
            short8 ah, al;
            #pragma unroll
            for (int j = 0; j < 8; ++j) {
                unsigned short h = f2bf(vv[j]);
                ah[j] = (short)h;
                al[j] = (short)f2bf(vv[j] - bf2f(h));
            }
            a_hi[rt][kt] = ah; a_lo[rt][kt] = al;
        }
    }

    // ee -> LDS once (broadcast reads in the loop, conflict-free)
    for (int i = t; i < 1024; i += 256) sEE[i] = ee[i];

    float b1[8], b2[8];
    int   i1[8];
    #pragma unroll
    for (int s = 0; s < 8; ++s) { b1[s] = 3.4e38f; b2[s] = 3.4e38f; i1[s] = 0; }

    const f32x4 zacc = {0.f, 0.f, 0.f, 0.f};

    __syncthreads();                      // sEE visible; only barrier pre-loop

    // main loop: 64 col-groups of 16 cols; B frags direct from L2.
    const uint4* bg = BfragG + lane;
    uint4 nb0 = bg[0], nb1 = bg[64], nb2 = bg[128], nb3 = bg[192];
    for (int g = 0; g < 64; ++g) {
        uint4 c_b0 = nb0, c_b1 = nb1, c_b2 = nb2, c_b3 = nb3;
        if (g < 63) {                     // rotating 1-group prefetch
            const uint4* p = bg + (g + 1) * 256;
            nb0 = p[0]; nb1 = p[64]; nb2 = p[128]; nb3 = p[192];
        }
        short8 bh0 = __builtin_bit_cast(short8, c_b0);
        short8 bl0 = __builtin_bit_cast(short8, c_b1);
        short8 bh1 = __builtin_bit_cast(short8, c_b2);
        short8 bl1 = __builtin_bit_cast(short8, c_b3);
        int col = g * 16 + wl;
        float eec = sEE[col];
        #pragma unroll
        for (int rt = 0; rt < 2; ++rt) {
            f32x4 c0 = __builtin_amdgcn_mfma_f32_16x16x32_bf16(a_lo[rt][0], bh0, zacc, 0, 0, 0);
            f32x4 c1 = __builtin_amdgcn_mfma_f32_16x16x32_bf16(a_lo[rt][1], bh1, zacc, 0, 0, 0);
            c0 = __builtin_amdgcn_mfma_f32_16x16x32_bf16(a_hi[rt][0], bl0, c0, 0, 0, 0);
            c1 = __builtin_amdgcn_mfma_f32_16x16x32_bf16(a_hi[rt][1], bl1, c1, 0, 0, 0);
            c0 = __builtin_amdgcn_mfma_f32_16x16x32_bf16(a_hi[rt][0], bh0, c0, 0, 0, 0);
            c1 = __builtin_amdgcn_mfma_f32_16x16x32_bf16(a_hi[rt][1], bh1, c1, 0, 0, 0);
            #pragma unroll
            for (int reg = 0; reg < 4; ++reg) {
                float s = c0[reg] + c1[reg] + eec;          // v_add3_f32
                int st = rt * 4 + reg;
                bool lt = s < b1[st];
                b2[st] = fminf(fmaxf(s, b1[st]), b2[st]);
                i1[st] = lt ? col : i1[st];
                b1[st] = fminf(s, b1[st]);
            }
        }
    }

    for (int m = 1; m < 16; m <<= 1) {
        #pragma unroll
        for (int s = 0; s < 8; ++s) {
            float ob1 = __shfl_xor(b1[s], m);
            int   oi1 = __shfl_xor(i1[s], m);
            float ob2 = __shfl_xor(b2[s], m);
            if (ob1 < b1[s] || (ob1 == b1[s] && oi1 < i1[s])) {
                b2[s] = fminf(b1[s], ob2); b1[s] = ob1; i1[s] = oi1;
            } else {
                b2[s] = fminf(b2[s], ob1);
            }
        }
    }
    if (wl == 0) {
        #pragma unroll
        for (int s = 0; s < 8; ++s) {
            int rt = s >> 2, reg = s & 3;
            int rloc = w * 32 + rt * 16 + quad * 4 + reg;
            int row = rbase + rloc;
            sIdx[rloc] = i1[s];
            ws_idx[row] = i1[s];
            out_ind[row] = (float)i1[s];
            if (b2[s] - b1[s] < TAU) {
                int pos = atomicAdd(ws_flagcnt, 1);
                if (pos < FLAG_CAP) ws_flaglist[pos] = row;
            }
        }
    }
    __syncthreads();

    {
        int r = t >> 1, hh = t & 1;
        int e = sIdx[r];
        const float4* et = (const float4*)(embedT + e * 64 + hh * 32);
        const float4* xr = (const float4*)(x + (size_t)(rbase + r) * 64 + hh * 32);
        float4*       qo = (float4*)(out_q + (size_t)(rbase + r) * 64 + hh * 32);
        float dsum = 0.f;
        #pragma unroll
        for (int v = 0; v < 8; ++v) {
            float4 q4 = et[v];
            float4 x4 = xr[v];
            float dx = q4.x - x4.x, dy = q4.y - x4.y, dz = q4.z - x4.z, dw = q4.w - x4.w;
            float4 o;
            o.x = x4.x + dx; o.y = x4.y + dy; o.z = x4.z + dz; o.w = x4.w + dw;
            qo[v] = o;
            dsum += dx * dx + dy * dy + dz * dz + dw * dw;
        }
        for (int o2 = 32; o2 > 0; o2 >>= 1) dsum += __shfl_down(dsum, o2);
        if (lane == 0) red[w] = dsum;
        __syncthreads();
        if (t == 0) atomicAdd(ws_diff, red[0] + red[1] + red[2] + red[3]);
    }
}

// ---------------- recheck: tiled exact fp32 re-argmin (R9 wave-parallel form)
__global__ __launch_bounds__(256) void recheck_kernel(
        const float* __restrict__ x, const float* __restrict__ embed,
        const float* __restrict__ embedT, const float* __restrict__ ee,
        const int* __restrict__ flagcnt, const int* __restrict__ flaglist,
        int* __restrict__ ws_idx, float* __restrict__ out_ind,
        float* __restrict__ out_q, float* __restrict__ ws_diff) {
    __shared__ float sx[8][64];
    __shared__ float sff[8];
    __shared__ int   srow[8];
    __shared__ float sbd[8][256];
    __shared__ int   sbi[8][256];
    const int t = threadIdx.x;
    const int w = t >> 6, lane = t & 63;
    int cnt = *flagcnt;
    if (cnt > FLAG_CAP) cnt = FLAG_CAP;
    int ntiles = (cnt + 7) >> 3;
    for (int tile = blockIdx.x; tile < ntiles; tile += gridDim.x) {
        int base = tile * 8;
        int nr = cnt - base; if (nr > 8) nr = 8;
        __syncthreads();                               // LDS reuse guard
        if (t < nr) srow[t] = flaglist[base + t];
        __syncthreads();
        for (int l = t; l < nr * 64; l += 256)
            sx[l >> 6][l & 63] = x[(size_t)srow[l >> 6] * 64 + (l & 63)];
        __syncthreads();
        if (t < nr) {
            float ff = 0.f;
            for (int k = 0; k < 64; ++k) ff = fmaf(sx[t][k], sx[t][k], ff);
            sff[t] = ff;
        }
        float acc[8][4];
        #pragma unroll
        for (int r = 0; r < 8; ++r)
            #pragma unroll
            for (int j = 0; j < 4; ++j) acc[r][j] = 0.f;
        int c0 = t * 4;
        for (int k = 0; k < 64; ++k) {
            float4 e4 = *(const float4*)(embed + k * 1024 + c0);
            #pragma unroll
            for (int r = 0; r < 8; ++r) {
                float xk = sx[r][k];
                acc[r][0] = fmaf(xk, e4.x, acc[r][0]);
                acc[r][1] = fmaf(xk, e4.y, acc[r][1]);
                acc[r][2] = fmaf(xk, e4.z, acc[r][2]);
                acc[r][3] = fmaf(xk, e4.w, acc[r][3]);
            }
        }
        __syncthreads();                               // sff visible
        #pragma unroll
        for (int r = 0; r < 8; ++r) {
            float ff = sff[r];
            float bd = 3.4e38f; int bi = 0;
            #pragma unroll
            for (int j = 0; j < 4; ++j) {
                float d = (ff - 2.f * acc[r][j]) + ee[c0 + j];
                if (d < bd) { bd = d; bi = c0 + j; }
            }
            sbd[r][t] = bd; sbi[r][t] = bi;
        }
        __syncthreads();
        #pragma unroll
        for (int rr = 0; rr < 2; ++rr) {
            int r = w * 2 + rr;
            if (r < nr) {
                float bd = sbd[r][lane]; int bi = sbi[r][lane];
                #pragma unroll
                for (int k2 = 1; k2 < 4; ++k2) {
                    float od = sbd[r][lane + 64 * k2];
                    int   oi = sbi[r][lane + 64 * k2];
                    if (od < bd || (od == bd && oi < bi)) { bd = od; bi = oi; }
                }
                for (int m = 32; m > 0; m >>= 1) {
                    float od = __shfl_xor(bd, m);
                    int   oi = __shfl_xor(bi, m);
                    if (od < bd || (od == bd && oi < bi)) { bd = od; bi = oi; }
                }
                int row = srow[r];
                int oi_old = ws_idx[row];               // broadcast load
                if (bi != oi_old) {
                    float xv = sx[r][lane];
                    float dn   = embedT[bi * 64 + lane] - xv;
                    float dold = embedT[oi_old * 64 + lane] - xv;
                    out_q[(size_t)row * 64 + lane] = xv + dn;
                    float delta = dn * dn - dold * dold;
                    for (int o = 32; o > 0; o >>= 1) delta += __shfl_down(delta, o);
                    if (lane == 0) {
                        ws_idx[row] = bi;
                        out_ind[row] = (float)bi;
                        atomicAdd(ws_diff, delta);
                    }
                }
            }
        }
    }
}

// ---------------- scatter: 32 ranges x 8 dim-octants; LDS hist [1024 codes][8 dims]
// R10/R11: [e][d] layout kills the 8-way same-bank conflict of [d][e]
// (d*1024 mod 32 == 0); 512 threads = 8 waves, 64 iters each.
__global__ __launch_bounds__(512) void scatter_kernel(
        const int* __restrict__ idx, const float* __restrict__ x,
        float* __restrict__ part_or_esum, float* __restrict__ cntp_or_cntf,
        int use_atomic) {
    __shared__ float shist[8192];         // [1024 codes][8 dims] = 32 KB
    __shared__ float scnt[1024];          // used by oct==0 blocks
    const int t = threadIdx.x;
    const int rb = blockIdx.x >> 3, oct = blockIdx.x & 7;      // 32 ranges x 8
    const int w = t >> 6, lane = t & 63;
    const int g = lane >> 3, d = lane & 7;                     // 8 rows x 8 dims

    for (int i = t; i < 8192; i += 512) shist[i] = 0.f;
    if (oct == 0) for (int i = t; i < 1024; i += 512) scnt[i] = 0.f;
    __syncthreads();

    const int row0 = rb * 4096 + w * 512;
    int rcur = row0 + g;
    int e_n = idx[rcur];
    float x_n = x[(size_t)rcur * 64 + oct * 8 + d];
    for (int it = 0; it < 64; ++it) {                  // 64 x 8 rows per wave
        int e = e_n; float xv = x_n;
        int rnext = rcur + 8;
        if (it < 63) {                                 // prefetch next iteration
            e_n = idx[rnext];
            x_n = x[(size_t)rnext * 64 + oct * 8 + d];
        }
        rcur = rnext;
        atomicAdd(&shist[e * 8 + d], xv);
        if (oct == 0 && d == 0) atomicAdd(&scnt[e], 1.0f);
    }
    __syncthreads();

    if (!use_atomic) {
        float* dst = part_or_esum + (size_t)blockIdx.x * 8192;
        for (int out = t; out < 8192; out += 512)      // out = dd*1024 + e
            dst[out] = shist[(out & 1023) * 8 + (out >> 10)];
        if (oct == 0) {
            float* cdst = cntp_or_cntf + rb * 1024;
            for (int i = t; i < 1024; i += 512) cdst[i] = scnt[i];
        }
    } else {
        for (int out = t; out < 8192; out += 512) {
            float v = shist[(out & 1023) * 8 + (out >> 10)];
            if (v != 0.f)
                atomicAdd(&part_or_esum[(oct * 8 + (out >> 10)) * 1024 + (out & 1023)], v);
        }
        if (oct == 0) {
            for (int i = t; i < 1024; i += 512) {
                float c = scnt[i];
                if (c != 0.f) atomicAdd(&cntp_or_cntf[i], c);
            }
        }
    }
}

// ---------------- finalize1: counts reduce + new_cluster_size, n, diff
__global__ __launch_bounds__(1024) void finalize1(
        const float* __restrict__ cluster_size, const float* __restrict__ cntp,
        int nrb, const float* __restrict__ ws_diff, float* __restrict__ out_diff,
        float* __restrict__ out_ncs, float* __restrict__ ws_n) {
    int t = threadIdx.x;
    float c = 0.f;
    for (int k = 0; k < nrb; ++k) c += cntp[k * 1024 + t];
    float ncs = DECAYF * cluster_size[t] + OMDF * c;
    out_ncs[t] = ncs;
    __shared__ float sred[16];
    float v = ncs;
    for (int o = 32; o > 0; o >>= 1) v += __shfl_down(v, o);
    if ((t & 63) == 0) sred[t >> 6] = v;
    __syncthreads();
    if (t == 0) {
        float n = 0.f;
        for (int i = 0; i < 16; ++i) n += sred[i];
        ws_n[0] = n;
        out_diff[0] = ws_diff[0] * (1.0f / 8388608.0f);   // /2^23 exact
    }
}

// ---------------- finalize2: partials reduce + new_embed_avg, new_embed
__global__ __launch_bounds__(256) void finalize2(
        const float* __restrict__ embed_avg, const float* __restrict__ part,
        int nrb, const float* __restrict__ out_ncs, const float* __restrict__ ws_n,
        float* __restrict__ out_nea, float* __restrict__ out_ne) {
    int j = blockIdx.x * 256 + threadIdx.x;      // < 65536 = dim*1024 + code
    float es = 0.f;
    for (int k = 0; k < nrb; ++k) es += part[(size_t)k * 65536 + j];
    float n = ws_n[0];
    float nea = DECAYF * embed_avg[j] + OMDF * es;
    out_nea[j] = nea;
    float ncs = out_ncs[j & 1023];
    float cs = (ncs + EPSF) / (n + NEPSF) * n;
    out_ne[j] = nea / cs;
}

extern "C" void kernel_launch(void* const* d_in, const int* in_sizes, int n_in,
                              void* d_out, int out_size, void* d_ws, size_t ws_size,
                              hipStream_t stream) {
    const float* x            = (const float*)d_in[0];
    const float* embed        = (const float*)d_in[1];
    const float* cluster_size = (const float*)d_in[2];
    const float* embed_avg    = (const float*)d_in[3];

    float* out = (float*)d_out;
    float* out_q    = out;                       // 8388608
    float* out_diff = out + 8388608;             // 1
    float* out_ind  = out + 8388609;             // 131072
    float* out_ncs  = out + 8519681;             // 1024
    float* out_nea  = out + 8520705;             // 65536
    float* out_ne   = out + 8586241;             // 65536

    float* ws = (float*)d_ws;
    float* ws_esum     = ws + WS_ESUM;
    float* ws_cntf     = ws + WS_CNTF;
    float* ws_diff     = ws + WS_DIFF;
    int*   ws_flagcnt  = (int*)(ws + WS_FLAGCNT);
    float* ws_n        = ws + WS_N;
    float* ws_ee       = ws + WS_EE;
    float* ws_embedT   = ws + WS_EMBEDT;
    int*   ws_idx      = (int*)(ws + WS_IDX);
    int*   ws_flaglist = (int*)(ws + WS_FLAGLST);
    uint4* ws_Bfrag    = (uint4*)(ws + WS_BFRAG);
    float* ws_cntpart  = ws + WS_CNTPART;
    float* ws_part     = ws + WS_PART;

    const int use_part = (ws_size >= WS_NEED_BYTES) ? 1 : 0;

    if (use_part) {
        hipMemsetAsync(ws + WS_DIFF, 0, 8, stream);          // diff + flagcnt only
    } else {
        hipMemsetAsync(d_ws, 0, (size_t)(WS_FLAGCNT + 1) * 4, stream);
    }

    prep_kernel<<<64, 256, 0, stream>>>(embed, ws_embedT, ws_ee, ws_Bfrag);
    dist_kernel<<<N_ROWS / 128, 256, 0, stream>>>(x, ws_Bfrag, ws_ee, ws_embedT,
                                                  out_q, out_ind, ws_idx, ws_diff,
                                                  ws_flagcnt, ws_flaglist);
    recheck_kernel<<<512, 256, 0, stream>>>(x, embed, ws_embedT, ws_ee,
                                            ws_flagcnt, ws_flaglist,
                                            ws_idx, out_ind, out_q, ws_diff);
    scatter_kernel<<<NRANGE * 8, 512, 0, stream>>>(
        ws_idx, x,
        use_part ? ws_part : ws_esum,
        use_part ? ws_cntpart : ws_cntf,
        use_part ? 0 : 1);
    finalize1<<<1, 1024, 0, stream>>>(cluster_size,
                                      use_part ? ws_cntpart : ws_cntf,
                                      use_part ? NRANGE : 1,
                                      ws_diff, out_diff, out_ncs, ws_n);
    finalize2<<<256, 256, 0, stream>>>(embed_avg,
                                       use_part ? ws_part : ws_esum,
                                       use_part ? NRANGE : 1,
                                       out_ncs, ws_n, out_nea, out_ne);
}